// Round 1
// baseline (437.144 us; speedup 1.0000x reference)
//
#include <hip/hip_runtime.h>

#define PTAB_STRIDE 64

// ---------------------------------------------------------------------------
// Phase 1: ptab[v][h] = sum_e emb[v][e] * W_ih[h][e] + b_ih[h]   (h<50, pad 0)
// 1024 waves; lane -> h; W_ih K-chunks (60 floats) in VGPRs; emb rows are
// wave-uniform broadcast float4 loads; 8 rows per block for ILP.
// ---------------------------------------------------------------------------
__global__ __launch_bounds__(256) void ptab_kernel(
    const float* __restrict__ emb, const float* __restrict__ Wih,
    const float* __restrict__ bih, float* __restrict__ ptab)
{
    const int lane  = threadIdx.x & 63;
    const int gwave = blockIdx.x * 4 + (threadIdx.x >> 6);   // 0..1023
    const int hc    = lane < 50 ? lane : 49;                 // clamp for safe loads
    const float bias = bih[hc];

    for (int rb = gwave; rb < 6250; rb += 1024) {            // 50000/8 = 6250 exact
        const int vbase = rb * 8;
        float acc[8] = {0.f,0.f,0.f,0.f,0.f,0.f,0.f,0.f};
        for (int c = 0; c < 5; ++c) {                        // 5 K-chunks of 60
            float4 w[15];
            const float4* wp = (const float4*)(Wih + hc * 300 + c * 60);
            #pragma unroll
            for (int j = 0; j < 15; ++j) w[j] = wp[j];
            #pragma unroll
            for (int r = 0; r < 8; ++r) {
                const float4* er =
                    (const float4*)(emb + (size_t)(vbase + r) * 300 + c * 60);
                #pragma unroll
                for (int j = 0; j < 15; ++j) {
                    float4 e = er[j];
                    acc[r] = fmaf(e.x, w[j].x, acc[r]);
                    acc[r] = fmaf(e.y, w[j].y, acc[r]);
                    acc[r] = fmaf(e.z, w[j].z, acc[r]);
                    acc[r] = fmaf(e.w, w[j].w, acc[r]);
                }
            }
        }
        #pragma unroll
        for (int r = 0; r < 8; ++r)
            ptab[(size_t)(vbase + r) * PTAB_STRIDE + lane] =
                (lane < 50) ? acc[r] + bias : 0.f;
    }
}

// ---------------------------------------------------------------------------
// Phase 2: recurrence + head. One wave per batch element.
// Lane l owns h[l]; h broadcast via v_readlane into SGPR, FMA'd against the
// lane's W_hh row held in 50 VGPRs. ptab gather prefetched 2 steps ahead.
// ---------------------------------------------------------------------------
__device__ __forceinline__ float bcast(float v, int l) {
    return __uint_as_float(__builtin_amdgcn_readlane(__float_as_uint(v), l));
}

__global__ __launch_bounds__(64) void rnn_kernel(
    const int* __restrict__ tokens, const float* __restrict__ ptab,
    const float* __restrict__ Whh, const float* __restrict__ bhh,
    const float* __restrict__ Wfc, const float* __restrict__ bfc,
    float* __restrict__ out)
{
    __shared__ int stok[520];
    const int lane = threadIdx.x;
    const int b    = blockIdx.x;
    const int hc   = lane < 50 ? lane : 49;

    #pragma unroll
    for (int k = 0; k < 8; ++k)
        stok[lane + 64 * k] = tokens[b * 512 + lane + 64 * k];
    if (lane < 8) stok[512 + lane] = 0;      // pad: token 0 -> valid row
    __syncthreads();

    float whh[50];
    #pragma unroll
    for (int j = 0; j < 50; j += 2) {
        float2 w2 = *(const float2*)(Whh + hc * 50 + j);
        whh[j] = w2.x; whh[j + 1] = w2.y;
    }
    const float bh = bhh[hc];

    float h = 0.f;
    int tA = stok[0], tB = stok[1];
    float x0 = ptab[(size_t)tA * PTAB_STRIDE + lane];
    float x1 = ptab[(size_t)tB * PTAB_STRIDE + lane];
    tA = stok[2]; tB = stok[3];

#define RNN_STEP(XV)                                                     \
    {                                                                    \
        float a0 = 0.f, a1 = 0.f, a2 = 0.f, a3 = 0.f;                    \
        _Pragma("unroll")                                                \
        for (int j = 0; j < 48; j += 4) {                                \
            a0 = fmaf(bcast(h, j + 0), whh[j + 0], a0);                  \
            a1 = fmaf(bcast(h, j + 1), whh[j + 1], a1);                  \
            a2 = fmaf(bcast(h, j + 2), whh[j + 2], a2);                  \
            a3 = fmaf(bcast(h, j + 3), whh[j + 3], a3);                  \
        }                                                                \
        a0 = fmaf(bcast(h, 48), whh[48], a0);                            \
        a1 = fmaf(bcast(h, 49), whh[49], a1);                            \
        float a = (XV) + bh + ((a0 + a1) + (a2 + a3));                   \
        a = fminf(9.f, fmaxf(-9.f, a));                                  \
        float e = __expf(2.f * a);                                       \
        h = fmaf(-2.f, __builtin_amdgcn_rcpf(e + 1.f), 1.f);             \
    }

    for (int t = 0; t < 512; t += 2) {
        float xa = ptab[(size_t)tA * PTAB_STRIDE + lane];  // prefetch t+2
        float xb = ptab[(size_t)tB * PTAB_STRIDE + lane];  // prefetch t+3
        tA = stok[t + 4];                                  // tokens for next iter
        tB = stok[t + 5];
        RNN_STEP(x0);
        RNN_STEP(x1);
        x0 = xa; x1 = xb;
    }
#undef RNN_STEP

    // ---- head: out[b][o] = sum_h h[h] * W_fc[o][h] + b_fc[o] ----
    float hv = (lane < 50) ? h : 0.f;
    #pragma unroll
    for (int o = 0; o < 4; ++o) {
        float w = (lane < 50) ? Wfc[o * 50 + lane] : 0.f;
        float p = hv * w;
        #pragma unroll
        for (int s = 32; s > 0; s >>= 1) p += __shfl_xor(p, s, 64);
        if (lane == 0) out[b * 4 + o] = p + bfc[o];
    }
}

extern "C" void kernel_launch(void* const* d_in, const int* in_sizes, int n_in,
                              void* d_out, int out_size, void* d_ws, size_t ws_size,
                              hipStream_t stream)
{
    const int*   tokens = (const int*)d_in[0];
    const float* emb    = (const float*)d_in[1];
    const float* Wih    = (const float*)d_in[2];
    const float* Whh    = (const float*)d_in[3];
    const float* bih    = (const float*)d_in[4];
    const float* bhh    = (const float*)d_in[5];
    const float* Wfc    = (const float*)d_in[6];
    const float* bfc    = (const float*)d_in[7];

    float* ptab = (float*)d_ws;          // 50000 * 64 * 4 B = 12.8 MB
    float* outp = (float*)d_out;

    ptab_kernel<<<256, 256, 0, stream>>>(emb, Wih, bih, ptab);
    rnn_kernel<<<256, 64, 0, stream>>>(tokens, ptab, Whh, bhh, Wfc, bfc, outp);
}

// Round 2
// 286.843 us; speedup vs baseline: 1.5240x; 1.5240x over previous
//
#include <hip/hip_runtime.h>

#define PTAB_STRIDE 64

// ---------------------------------------------------------------------------
// Phase 1: ptab[v][h] = dot(emb[v,:], W_ih[h,:]) + b_ih[h] + b_hh[h]
// 1563 blocks x 256 threads. Each block stages a contiguous 32x300 emb slab
// into LDS (38.4 KB -> 4 blocks/CU), then each wave computes 8 rows with
// lane->h mapping: W chunk (60 floats) in VGPRs, emb via LDS broadcast reads.
// ---------------------------------------------------------------------------
__global__ __launch_bounds__(256) void ptab_kernel(
    const float* __restrict__ emb, const float* __restrict__ Wih,
    const float* __restrict__ bih, const float* __restrict__ bhh,
    float* __restrict__ ptab)
{
    __shared__ __align__(16) float tile[32 * 300];   // 38400 B
    const int tid  = threadIdx.x;
    const int lane = tid & 63;
    const int wid  = tid >> 6;
    const int hc   = lane < 50 ? lane : 49;          // clamp for safe loads

    const int v0    = blockIdx.x * 32;
    const int nrows = min(32, 50000 - v0);
    const int nch   = nrows * 75;                    // 16B chunks in the slab

    const float4* src4 = (const float4*)(emb + (size_t)v0 * 300);
    float4*       t4   = (float4*)tile;

    if (nch == 2400) {                               // all but the last block
        // two-phase staging: 9-10 independent loads in flight, then writes
        float4 s0 = src4[tid];
        float4 s1 = src4[tid + 256];
        float4 s2 = src4[tid + 512];
        float4 s3 = src4[tid + 768];
        float4 s4 = src4[tid + 1024];
        float4 s5 = src4[tid + 1280];
        float4 s6 = src4[tid + 1536];
        float4 s7 = src4[tid + 1792];
        float4 s8 = src4[tid + 2048];
        const bool e9 = tid < 96;                    // 2400 - 9*256 = 96
        float4 s9;
        if (e9) s9 = src4[tid + 2304];
        t4[tid]        = s0;
        t4[tid + 256]  = s1;
        t4[tid + 512]  = s2;
        t4[tid + 768]  = s3;
        t4[tid + 1024] = s4;
        t4[tid + 1280] = s5;
        t4[tid + 1536] = s6;
        t4[tid + 1792] = s7;
        t4[tid + 2048] = s8;
        if (e9) t4[tid + 2304] = s9;
    } else {                                         // tail block (16 rows)
        for (int i = tid; i < nch; i += 256) t4[i] = src4[i];
    }
    __syncthreads();

    float acc[8] = {0.f,0.f,0.f,0.f,0.f,0.f,0.f,0.f};
    for (int c = 0; c < 5; ++c) {                    // 5 K-chunks of 60
        float4 w[15];
        const float4* wp = (const float4*)(Wih + hc * 300 + c * 60);
        #pragma unroll
        for (int j = 0; j < 15; ++j) w[j] = wp[j];   // L2-hot after 1st tile
        #pragma unroll
        for (int r = 0; r < 8; ++r) {
            const float4* er =
                (const float4*)(tile + (wid * 8 + r) * 300 + c * 60);
            #pragma unroll
            for (int j = 0; j < 15; ++j) {
                float4 e = er[j];                    // LDS broadcast read
                acc[r] = fmaf(e.x, w[j].x, acc[r]);
                acc[r] = fmaf(e.y, w[j].y, acc[r]);
                acc[r] = fmaf(e.z, w[j].z, acc[r]);
                acc[r] = fmaf(e.w, w[j].w, acc[r]);
            }
        }
    }

    const float bias = (lane < 50) ? bih[hc] + bhh[hc] : 0.f;
    #pragma unroll
    for (int r = 0; r < 8; ++r) {
        const int gv = v0 + wid * 8 + r;
        if (gv < 50000)
            ptab[(size_t)gv * PTAB_STRIDE + lane] =
                (lane < 50) ? acc[r] + bias : 0.f;
    }
}

// ---------------------------------------------------------------------------
// Phase 2: recurrence + head. One wave per batch element.
// Lane l owns h[l]; h broadcast via v_readlane, FMA'd against the lane's
// W_hh row held in 50 VGPRs. ptab gather prefetched 2 steps ahead.
// b_hh is pre-folded into ptab.
// ---------------------------------------------------------------------------
__device__ __forceinline__ float bcast(float v, int l) {
    return __uint_as_float(__builtin_amdgcn_readlane(__float_as_uint(v), l));
}

__global__ __launch_bounds__(64) void rnn_kernel(
    const int* __restrict__ tokens, const float* __restrict__ ptab,
    const float* __restrict__ Whh,
    const float* __restrict__ Wfc, const float* __restrict__ bfc,
    float* __restrict__ out)
{
    __shared__ int stok[520];
    const int lane = threadIdx.x;
    const int b    = blockIdx.x;
    const int hc   = lane < 50 ? lane : 49;

    #pragma unroll
    for (int k = 0; k < 8; ++k)
        stok[lane + 64 * k] = tokens[b * 512 + lane + 64 * k];
    if (lane < 8) stok[512 + lane] = 0;      // pad: token 0 -> valid row
    __syncthreads();

    float whh[50];
    #pragma unroll
    for (int j = 0; j < 50; j += 2) {
        float2 w2 = *(const float2*)(Whh + hc * 50 + j);
        whh[j] = w2.x; whh[j + 1] = w2.y;
    }

    float h = 0.f;
    int tA = stok[0], tB = stok[1];
    float x0 = ptab[(size_t)tA * PTAB_STRIDE + lane];
    float x1 = ptab[(size_t)tB * PTAB_STRIDE + lane];
    tA = stok[2]; tB = stok[3];

#define RNN_STEP(XV)                                                     \
    {                                                                    \
        float a0 = 0.f, a1 = 0.f, a2 = 0.f, a3 = 0.f;                    \
        _Pragma("unroll")                                                \
        for (int j = 0; j < 48; j += 4) {                                \
            a0 = fmaf(bcast(h, j + 0), whh[j + 0], a0);                  \
            a1 = fmaf(bcast(h, j + 1), whh[j + 1], a1);                  \
            a2 = fmaf(bcast(h, j + 2), whh[j + 2], a2);                  \
            a3 = fmaf(bcast(h, j + 3), whh[j + 3], a3);                  \
        }                                                                \
        a0 = fmaf(bcast(h, 48), whh[48], a0);                            \
        a1 = fmaf(bcast(h, 49), whh[49], a1);                            \
        float a = (XV) + ((a0 + a1) + (a2 + a3));                        \
        a = fminf(9.f, fmaxf(-9.f, a));                                  \
        float e = __expf(2.f * a);                                       \
        h = fmaf(-2.f, __builtin_amdgcn_rcpf(e + 1.f), 1.f);             \
    }

    for (int t = 0; t < 512; t += 2) {
        float xa = ptab[(size_t)tA * PTAB_STRIDE + lane];  // prefetch t+2
        float xb = ptab[(size_t)tB * PTAB_STRIDE + lane];  // prefetch t+3
        tA = stok[t + 4];
        tB = stok[t + 5];
        RNN_STEP(x0);
        RNN_STEP(x1);
        x0 = xa; x1 = xb;
    }
#undef RNN_STEP

    // ---- head: out[b][o] = sum_h h[h] * W_fc[o][h] + b_fc[o] ----
    float hv = (lane < 50) ? h : 0.f;
    #pragma unroll
    for (int o = 0; o < 4; ++o) {
        float w = (lane < 50) ? Wfc[o * 50 + lane] : 0.f;
        float p = hv * w;
        #pragma unroll
        for (int s = 32; s > 0; s >>= 1) p += __shfl_xor(p, s, 64);
        if (lane == 0) out[b * 4 + o] = p + bfc[o];
    }
}

extern "C" void kernel_launch(void* const* d_in, const int* in_sizes, int n_in,
                              void* d_out, int out_size, void* d_ws, size_t ws_size,
                              hipStream_t stream)
{
    const int*   tokens = (const int*)d_in[0];
    const float* emb    = (const float*)d_in[1];
    const float* Wih    = (const float*)d_in[2];
    const float* Whh    = (const float*)d_in[3];
    const float* bih    = (const float*)d_in[4];
    const float* bhh    = (const float*)d_in[5];
    const float* Wfc    = (const float*)d_in[6];
    const float* bfc    = (const float*)d_in[7];

    float* ptab = (float*)d_ws;          // 50000 * 64 * 4 B = 12.8 MB
    float* outp = (float*)d_out;

    ptab_kernel<<<1563, 256, 0, stream>>>(emb, Wih, bih, bhh, ptab);
    rnn_kernel<<<256, 64, 0, stream>>>(tokens, ptab, Whh, Wfc, bfc, outp);
}

// Round 3
// 194.485 us; speedup vs baseline: 2.2477x; 1.4749x over previous
//
#include <hip/hip_runtime.h>

#define PTAB_STRIDE 64

// ---------------------------------------------------------------------------
// Phase 1: ptab[v][h] = dot(emb[v,:], W_ih[h,:]) + b_ih[h] + b_hh[h]
// 3125 blocks x 256 threads (50000 = 3125*16 exact). Each block stages a
// contiguous 16x300 emb slab into LDS (19.2 KB -> 8 blocks/CU so staging of
// some blocks overlaps compute of others). Lane->h mapping; W chunk (60
// floats) in VGPRs; emb rows via wave-uniform LDS broadcast reads.
// ---------------------------------------------------------------------------
__global__ __launch_bounds__(256) void ptab_kernel(
    const float* __restrict__ emb, const float* __restrict__ Wih,
    const float* __restrict__ bih, const float* __restrict__ bhh,
    float* __restrict__ ptab)
{
    __shared__ __align__(16) float tile[16 * 300];   // 19200 B
    const int tid  = threadIdx.x;
    const int lane = tid & 63;
    const int wid  = tid >> 6;
    const int hc   = lane < 50 ? lane : 49;          // clamp for safe loads

    const int v0 = blockIdx.x * 16;
    const float4* src4 = (const float4*)(emb + (size_t)v0 * 300);
    float4*       t4   = (float4*)tile;

    // 1200 16B chunks: 4 full rounds + 176 tail; loads first, writes after.
    float4 s0 = src4[tid];
    float4 s1 = src4[tid + 256];
    float4 s2 = src4[tid + 512];
    float4 s3 = src4[tid + 768];
    const bool e4 = tid < 176;
    float4 s4;
    if (e4) s4 = src4[tid + 1024];
    t4[tid]        = s0;
    t4[tid + 256]  = s1;
    t4[tid + 512]  = s2;
    t4[tid + 768]  = s3;
    if (e4) t4[tid + 1024] = s4;
    __syncthreads();

    float acc[4] = {0.f, 0.f, 0.f, 0.f};
    for (int c = 0; c < 5; ++c) {                    // 5 K-chunks of 60
        float4 w[15];
        const float4* wp = (const float4*)(Wih + hc * 300 + c * 60);
        #pragma unroll
        for (int j = 0; j < 15; ++j) w[j] = wp[j];   // L1/L2-hot (12 KB table)
        #pragma unroll
        for (int r = 0; r < 4; ++r) {
            const float4* er =
                (const float4*)(tile + (wid * 4 + r) * 300 + c * 60);
            #pragma unroll
            for (int j = 0; j < 15; ++j) {
                float4 e = er[j];                    // LDS broadcast read
                acc[r] = fmaf(e.x, w[j].x, acc[r]);
                acc[r] = fmaf(e.y, w[j].y, acc[r]);
                acc[r] = fmaf(e.z, w[j].z, acc[r]);
                acc[r] = fmaf(e.w, w[j].w, acc[r]);
            }
        }
    }

    const float bias = (lane < 50) ? bih[hc] + bhh[hc] : 0.f;
    #pragma unroll
    for (int r = 0; r < 4; ++r)
        ptab[(size_t)(v0 + wid * 4 + r) * PTAB_STRIDE + lane] =
            (lane < 50) ? acc[r] + bias : 0.f;
}

// ---------------------------------------------------------------------------
// Phase 2: recurrence + head. One wave per batch element.
// Lane l owns h[l]. Broadcasts of h[j] use ds_bpermute (VGPR->VGPR, no SGPR
// RAW hazard). x gathers prefetched 8 steps ahead; token indices register-
// prefetched one full iteration ahead. b_hh pre-folded into ptab.
// ---------------------------------------------------------------------------
__device__ __forceinline__ float bc(float v, int j) {
    return __uint_as_float(
        __builtin_amdgcn_ds_bpermute(j * 4, __float_as_uint(v)));
}

__global__ __launch_bounds__(64) void rnn_kernel(
    const int* __restrict__ tokens, const float* __restrict__ ptab,
    const float* __restrict__ Whh,
    const float* __restrict__ Wfc, const float* __restrict__ bfc,
    float* __restrict__ out)
{
    __shared__ int stok[544];
    const int lane = threadIdx.x;
    const int b    = blockIdx.x;
    const int hc   = lane < 50 ? lane : 49;

    #pragma unroll
    for (int k = 0; k < 8; ++k)
        stok[lane + 64 * k] = tokens[b * 512 + lane + 64 * k];
    if (lane < 32) stok[512 + lane] = 0;     // pad: token 0 -> valid row
    __syncthreads();

    float whh[50];
    #pragma unroll
    for (int j = 0; j < 50; j += 2) {
        float2 w2 = *(const float2*)(Whh + hc * 50 + j);
        whh[j] = w2.x; whh[j + 1] = w2.y;
    }

    float h = 0.f;

#define GATHER(T) ptab[(size_t)(T) * PTAB_STRIDE + lane]

    // steps 0..7 in flight
    float x0 = GATHER(stok[0]), x1 = GATHER(stok[1]);
    float x2 = GATHER(stok[2]), x3 = GATHER(stok[3]);
    float x4 = GATHER(stok[4]), x5 = GATHER(stok[5]);
    float x6 = GATHER(stok[6]), x7 = GATHER(stok[7]);
    // token indices for steps 8..15
    int k0 = stok[8],  k1 = stok[9],  k2 = stok[10], k3 = stok[11];
    int k4 = stok[12], k5 = stok[13], k6 = stok[14], k7 = stok[15];

#define RNN_STEP(XV)                                                     \
    {                                                                    \
        float a0 = 0.f, a1 = 0.f, a2 = 0.f, a3 = 0.f;                    \
        _Pragma("unroll")                                                \
        for (int j = 0; j < 48; j += 4) {                                \
            a0 = fmaf(bc(h, j + 0), whh[j + 0], a0);                     \
            a1 = fmaf(bc(h, j + 1), whh[j + 1], a1);                     \
            a2 = fmaf(bc(h, j + 2), whh[j + 2], a2);                     \
            a3 = fmaf(bc(h, j + 3), whh[j + 3], a3);                     \
        }                                                                \
        a0 = fmaf(bc(h, 48), whh[48], a0);                               \
        a1 = fmaf(bc(h, 49), whh[49], a1);                               \
        float a = (XV) + ((a0 + a1) + (a2 + a3));                        \
        a = fminf(9.f, fmaxf(-9.f, a));                                  \
        float e = __expf(2.f * a);                                       \
        h = fmaf(-2.f, __builtin_amdgcn_rcpf(e + 1.f), 1.f);             \
    }

    for (int t = 0; t < 512; t += 8) {
        // issue gathers for steps t+8 .. t+15
        float n0 = GATHER(k0), n1 = GATHER(k1), n2 = GATHER(k2), n3 = GATHER(k3);
        float n4 = GATHER(k4), n5 = GATHER(k5), n6 = GATHER(k6), n7 = GATHER(k7);
        // token indices for the NEXT iteration's gathers (steps t+16..t+23)
        k0 = stok[t + 16]; k1 = stok[t + 17]; k2 = stok[t + 18]; k3 = stok[t + 19];
        k4 = stok[t + 20]; k5 = stok[t + 21]; k6 = stok[t + 22]; k7 = stok[t + 23];

        RNN_STEP(x0); RNN_STEP(x1); RNN_STEP(x2); RNN_STEP(x3);
        RNN_STEP(x4); RNN_STEP(x5); RNN_STEP(x6); RNN_STEP(x7);

        x0 = n0; x1 = n1; x2 = n2; x3 = n3;
        x4 = n4; x5 = n5; x6 = n6; x7 = n7;
    }
#undef RNN_STEP
#undef GATHER

    // ---- head: out[b][o] = sum_h h[h] * W_fc[o][h] + b_fc[o] ----
    float hv = (lane < 50) ? h : 0.f;
    #pragma unroll
    for (int o = 0; o < 4; ++o) {
        float w = (lane < 50) ? Wfc[o * 50 + lane] : 0.f;
        float p = hv * w;
        #pragma unroll
        for (int s = 32; s > 0; s >>= 1) p += __shfl_xor(p, s, 64);
        if (lane == 0) out[b * 4 + o] = p + bfc[o];
    }
}

extern "C" void kernel_launch(void* const* d_in, const int* in_sizes, int n_in,
                              void* d_out, int out_size, void* d_ws, size_t ws_size,
                              hipStream_t stream)
{
    const int*   tokens = (const int*)d_in[0];
    const float* emb    = (const float*)d_in[1];
    const float* Wih    = (const float*)d_in[2];
    const float* Whh    = (const float*)d_in[3];
    const float* bih    = (const float*)d_in[4];
    const float* bhh    = (const float*)d_in[5];
    const float* Wfc    = (const float*)d_in[6];
    const float* bfc    = (const float*)d_in[7];

    float* ptab = (float*)d_ws;          // 50000 * 64 * 4 B = 12.8 MB
    float* outp = (float*)d_out;

    ptab_kernel<<<3125, 256, 0, stream>>>(emb, Wih, bih, bhh, ptab);
    rnn_kernel<<<256, 64, 0, stream>>>(tokens, ptab, Whh, Wfc, bfc, outp);
}